// Round 6
// baseline (351.502 us; speedup 1.0000x reference)
//
#include <hip/hip_runtime.h>
#include <hip/hip_bf16.h>

// QuantLinear: out[m][n] = (sum_k in[m][k]*(q[n][k]-128)) * scale[n] + bias[n]
// M=512, K=4096, N=11008. A fp32, Q int32 (0..255), out fp32.
//
// R6: stop fighting the scheduler (R3-R5: VGPR tell showed prefetch sets were
// never co-live; the unfenced COMPUTE/STORES boundary let the pre-RA scheduler
// hoist stores above MFMA). Move to the HW-verified m97 structure:
//   P1: A fp32 -> bf16           (12 MB traffic)
//   P2: Q int32 -> bf16(q-128)   (exact, |q-128|<=128; 270 MB traffic)
//   GEMM: pure-bf16, global_load_lds staging (no staging VGPRs, no VALU
//         conversion), 2-barrier loop, 4 blocks/CU TLP hides the vmcnt drain.
// LDS conflicts: rule #21 — linear LDS dest + inverse-swizzled per-lane
// global SOURCE + XOR-swizzled ds_read (same algebra R5 verified).
// Guard: needs ~94.4 MB of d_ws; falls back to the R5 kernel if smaller.

#define BM 64
#define BN 128
#define BK 64

typedef __attribute__((ext_vector_type(8))) short bf16x8;
typedef __attribute__((ext_vector_type(4))) float f32x4;
typedef __attribute__((ext_vector_type(4))) int   i32x4;

__device__ __forceinline__ unsigned short f2bf(float x) {
  __hip_bfloat16 h = __float2bfloat16(x);
  return *reinterpret_cast<unsigned short*>(&h);
}

#define GLOAD16(gptr, lptr)                                                  \
  __builtin_amdgcn_global_load_lds(                                          \
      (const __attribute__((address_space(1))) void*)(gptr),                 \
      (__attribute__((address_space(3))) void*)(lptr), 16, 0, 0)

// ---------------- P1: A fp32 -> bf16 ----------------
__global__ __launch_bounds__(256)
void cvtA_kernel(const float* __restrict__ A, unsigned short* __restrict__ Abf,
                 int nquad) {
  const int stride = gridDim.x * 256;
  for (int i = blockIdx.x * 256 + threadIdx.x; i < nquad; i += stride) {
    f32x4 v = *reinterpret_cast<const f32x4*>(A + (size_t)i * 4);
    ushort4 h;
    h.x = f2bf(v.x); h.y = f2bf(v.y); h.z = f2bf(v.z); h.w = f2bf(v.w);
    *reinterpret_cast<ushort4*>(Abf + (size_t)i * 4) = h;
  }
}

// ---------------- P2: Q int32 -> bf16(q-128) ----------------
__global__ __launch_bounds__(256)
void cvtQ_kernel(const int* __restrict__ Q, unsigned short* __restrict__ Qbf,
                 int nquad) {
  const int stride = gridDim.x * 256;
  for (int i = blockIdx.x * 256 + threadIdx.x; i < nquad; i += stride) {
    i32x4 v = *reinterpret_cast<const i32x4*>(Q + (size_t)i * 4);
    ushort4 h;
    h.x = f2bf((float)(v.x - 128));
    h.y = f2bf((float)(v.y - 128));
    h.z = f2bf((float)(v.z - 128));
    h.w = f2bf((float)(v.w - 128));
    *reinterpret_cast<ushort4*>(Qbf + (size_t)i * 4) = h;
  }
}

// ---------------- fast-path GEMM: bf16 x bf16, gload_lds staging ----------
__global__ __launch_bounds__(256, 4)
void qgemm_kernel(const unsigned short* __restrict__ Abf, // [M][K] bf16
                  const unsigned short* __restrict__ Qbf, // [N][K] bf16(q-128)
                  const float* __restrict__ scale,        // [N]
                  const float* __restrict__ bias,         // [N]
                  float* __restrict__ C,                  // [M][N]
                  int M, int N, int K)
{
  __shared__ unsigned short sA[BM][BK];   //  8 KB
  __shared__ unsigned short sB[BN][BK];   // 16 KB

  const int tid  = threadIdx.x;
  const int lane = tid & 63;
  const int wave = tid >> 6;
  const int wr   = wave >> 1;
  const int wc   = wave & 1;

  const int nbm = M / BM;                 // 8
  const int nwg = gridDim.x;              // 688 (div by 8)
  int wgid = blockIdx.x;
  if ((nwg & 7) == 0) wgid = (wgid & 7) * (nwg >> 3) + (wgid >> 3);
  const int bm   = wgid % nbm;
  const int bn   = wgid / nbm;
  const int row0 = bm * BM;
  const int col0 = bn * BN;

  // ---- staging chunk setup: 24 x 1KB chunks, wave w owns chunks 6w..6w+5.
  // chunk c<8 : sA rows [8c, 8c+8);  c>=8 : sB rows [8(c-8), ...).
  // HW writes LDS at (uniform base + lane*16). Inverse-swizzled SOURCE:
  // LDS row = 8c + (lane>>3), content(row, elem e) = global elem
  // e ^ ((row&7)<<3);  per-lane src col8 = (lane&7) ^ (lane>>3).
  const int rsub = lane >> 3;                         // 0..7 (= row&7)
  const int col8 = ((lane & 7) ^ rsub) << 3;          // swizzled 8-elem block

#define CHUNK_SETUP(j, gvar, lvar)                                           \
  const unsigned short* gvar; unsigned short* lvar;                          \
  {                                                                          \
    const int c = wave * 6 + (j);                                            \
    if (c < 8) {                                                             \
      lvar = &sA[c * 8][0];                                                  \
      gvar = Abf + (size_t)(row0 + c * 8 + rsub) * K + col8;                 \
    } else {                                                                 \
      lvar = &sB[(c - 8) * 8][0];                                            \
      gvar = Qbf + (size_t)(col0 + (c - 8) * 8 + rsub) * K + col8;           \
    }                                                                        \
  }
  CHUNK_SETUP(0, g0, l0)
  CHUNK_SETUP(1, g1, l1)
  CHUNK_SETUP(2, g2, l2)
  CHUNK_SETUP(3, g3, l3)
  CHUNK_SETUP(4, g4, l4)
  CHUNK_SETUP(5, g5, l5)
#undef CHUNK_SETUP

  f32x4 acc[2][4];
#pragma unroll
  for (int i = 0; i < 2; ++i)
#pragma unroll
    for (int j = 0; j < 4; ++j) acc[i][j] = (f32x4)0.0f;

  const int cl  = lane & 15;
  const int kgr = (lane >> 4) << 3;       // k-group base elem (0,8,16,24)

  for (int kt = 0; kt < K; kt += BK) {
    GLOAD16(g0 + kt, l0);
    GLOAD16(g1 + kt, l1);
    GLOAD16(g2 + kt, l2);
    GLOAD16(g3 + kt, l3);
    GLOAD16(g4 + kt, l4);
    GLOAD16(g5 + kt, l5);
    __syncthreads();                      // vmcnt(0)+barrier: TLP absorbs

#pragma unroll
    for (int kk = 0; kk < BK; kk += 32) {
      const int kb = kk + kgr;
      bf16x8 af0, af1, bv0, bv1, bv2, bv3;
      {
        const int r0 = wr * 32 + 0  + cl;
        const int r1 = wr * 32 + 16 + cl;
        af0 = *(const bf16x8*)&sA[r0][kb ^ ((r0 & 7) << 3)];
        af1 = *(const bf16x8*)&sA[r1][kb ^ ((r1 & 7) << 3)];
        const int s0 = wc * 64 + 0  + cl;
        const int s1 = wc * 64 + 16 + cl;
        const int s2 = wc * 64 + 32 + cl;
        const int s3 = wc * 64 + 48 + cl;
        bv0 = *(const bf16x8*)&sB[s0][kb ^ ((s0 & 7) << 3)];
        bv1 = *(const bf16x8*)&sB[s1][kb ^ ((s1 & 7) << 3)];
        bv2 = *(const bf16x8*)&sB[s2][kb ^ ((s2 & 7) << 3)];
        bv3 = *(const bf16x8*)&sB[s3][kb ^ ((s3 & 7) << 3)];
      }
      acc[0][0] = __builtin_amdgcn_mfma_f32_16x16x32_bf16(af0, bv0, acc[0][0], 0,0,0);
      acc[0][1] = __builtin_amdgcn_mfma_f32_16x16x32_bf16(af0, bv1, acc[0][1], 0,0,0);
      acc[0][2] = __builtin_amdgcn_mfma_f32_16x16x32_bf16(af0, bv2, acc[0][2], 0,0,0);
      acc[0][3] = __builtin_amdgcn_mfma_f32_16x16x32_bf16(af0, bv3, acc[0][3], 0,0,0);
      acc[1][0] = __builtin_amdgcn_mfma_f32_16x16x32_bf16(af1, bv0, acc[1][0], 0,0,0);
      acc[1][1] = __builtin_amdgcn_mfma_f32_16x16x32_bf16(af1, bv1, acc[1][1], 0,0,0);
      acc[1][2] = __builtin_amdgcn_mfma_f32_16x16x32_bf16(af1, bv2, acc[1][2], 0,0,0);
      acc[1][3] = __builtin_amdgcn_mfma_f32_16x16x32_bf16(af1, bv3, acc[1][3], 0,0,0);
    }
    __syncthreads();
  }

  // epilogue: D col = lane&15 (n), row = (lane>>4)*4 + reg (m)  [m89/m91]
  const int rb = row0 + wr * 32 + ((lane >> 4) << 2);
#pragma unroll
  for (int ni = 0; ni < 4; ++ni) {
    const int n = col0 + wc * 64 + ni * 16 + cl;
    const float s = scale[n];
    const float b = bias[n];
#pragma unroll
    for (int mi = 0; mi < 2; ++mi) {
#pragma unroll
      for (int r = 0; r < 4; ++r) {
        C[(size_t)(rb + mi * 16 + r) * N + n] = acc[mi][ni][r] * s + b;
      }
    }
  }
}

// ================= R5 fallback (ws too small) =================
__global__ __launch_bounds__(256)
void rowsum_kernel(const float* __restrict__ A, float* __restrict__ rs, int K) {
  const int row = blockIdx.x;
  const int tid = threadIdx.x;
  const float4* Ar = reinterpret_cast<const float4*>(A + (size_t)row * K);
  const int nv4 = K >> 2;
  float s = 0.f;
  for (int i = tid; i < nv4; i += 256) {
    float4 v = Ar[i];
    s += (v.x + v.y) + (v.z + v.w);
  }
#pragma unroll
  for (int off = 32; off > 0; off >>= 1) s += __shfl_down(s, off, 64);
  __shared__ float ws[4];
  if ((tid & 63) == 0) ws[tid >> 6] = s;
  __syncthreads();
  if (tid == 0) rs[row] = (ws[0] + ws[1]) + (ws[2] + ws[3]);
}

#define LOADS(s, ke) do {                                                   \
  a##s##_0 = *(const f32x4*)(Abase + (size_t)( 0) * K + (ke));              \
  a##s##_1 = *(const f32x4*)(Abase + (size_t)(16) * K + (ke));              \
  a##s##_2 = *(const f32x4*)(Abase + (size_t)(32) * K + (ke));              \
  a##s##_3 = *(const f32x4*)(Abase + (size_t)(48) * K + (ke));              \
  q##s##_0 = *(const i32x4*)(Qbase + (size_t)(  0) * K + (ke));             \
  q##s##_1 = *(const i32x4*)(Qbase + (size_t)( 16) * K + (ke));             \
  q##s##_2 = *(const i32x4*)(Qbase + (size_t)( 32) * K + (ke));             \
  q##s##_3 = *(const i32x4*)(Qbase + (size_t)( 48) * K + (ke));             \
  q##s##_4 = *(const i32x4*)(Qbase + (size_t)( 64) * K + (ke));             \
  q##s##_5 = *(const i32x4*)(Qbase + (size_t)( 80) * K + (ke));             \
  q##s##_6 = *(const i32x4*)(Qbase + (size_t)( 96) * K + (ke));             \
  q##s##_7 = *(const i32x4*)(Qbase + (size_t)(112) * K + (ke));             \
} while (0)

#define ST_A(b, it, reg) do {                                               \
  ushort4 h;                                                                \
  h.x = f2bf(reg.x); h.y = f2bf(reg.y); h.z = f2bf(reg.z); h.w = f2bf(reg.w); \
  *(ushort4*)&sA[b][(it)*16 + sr][swzc] = h;                                \
} while (0)

#define ST_Q(b, it, reg) do {                                               \
  ushort4 h;                                                                \
  h.x = f2bf((float)reg.x); h.y = f2bf((float)reg.y);                       \
  h.z = f2bf((float)reg.z); h.w = f2bf((float)reg.w);                       \
  *(ushort4*)&sB[b][(it)*16 + sr][swzc] = h;                                \
} while (0)

#define STORES(s, b) do {                                                   \
  ST_A(b, 0, a##s##_0); ST_A(b, 1, a##s##_1);                               \
  ST_A(b, 2, a##s##_2); ST_A(b, 3, a##s##_3);                               \
  ST_Q(b, 0, q##s##_0); ST_Q(b, 1, q##s##_1);                               \
  ST_Q(b, 2, q##s##_2); ST_Q(b, 3, q##s##_3);                               \
  ST_Q(b, 4, q##s##_4); ST_Q(b, 5, q##s##_5);                               \
  ST_Q(b, 6, q##s##_6); ST_Q(b, 7, q##s##_7);                               \
} while (0)

#define COMPUTE(b) do {                                                     \
  _Pragma("unroll")                                                         \
  for (int kk = 0; kk < BK; kk += 32) {                                     \
    const int kb  = (kk + ((lane >> 4) << 3)) ^ ((lane & 7) << 3);          \
    bf16x8 af0 = *(const bf16x8*)&sA[b][wr*32 +  0 + (lane & 15)][kb];      \
    bf16x8 af1 = *(const bf16x8*)&sA[b][wr*32 + 16 + (lane & 15)][kb];      \
    bf16x8 bv0 = *(const bf16x8*)&sB[b][wc*64 +  0 + (lane & 15)][kb];      \
    bf16x8 bv1 = *(const bf16x8*)&sB[b][wc*64 + 16 + (lane & 15)][kb];      \
    bf16x8 bv2 = *(const bf16x8*)&sB[b][wc*64 + 32 + (lane & 15)][kb];      \
    bf16x8 bv3 = *(const bf16x8*)&sB[b][wc*64 + 48 + (lane & 15)][kb];      \
    acc[0][0] = __builtin_amdgcn_mfma_f32_16x16x32_bf16(af0, bv0, acc[0][0], 0,0,0); \
    acc[0][1] = __builtin_amdgcn_mfma_f32_16x16x32_bf16(af0, bv1, acc[0][1], 0,0,0); \
    acc[0][2] = __builtin_amdgcn_mfma_f32_16x16x32_bf16(af0, bv2, acc[0][2], 0,0,0); \
    acc[0][3] = __builtin_amdgcn_mfma_f32_16x16x32_bf16(af0, bv3, acc[0][3], 0,0,0); \
    acc[1][0] = __builtin_amdgcn_mfma_f32_16x16x32_bf16(af1, bv0, acc[1][0], 0,0,0); \
    acc[1][1] = __builtin_amdgcn_mfma_f32_16x16x32_bf16(af1, bv1, acc[1][1], 0,0,0); \
    acc[1][2] = __builtin_amdgcn_mfma_f32_16x16x32_bf16(af1, bv2, acc[1][2], 0,0,0); \
    acc[1][3] = __builtin_amdgcn_mfma_f32_16x16x32_bf16(af1, bv3, acc[1][3], 0,0,0); \
  }                                                                         \
} while (0)

#define BARX() do {                                                         \
  asm volatile("s_waitcnt lgkmcnt(0)" ::: "memory");                        \
  __builtin_amdgcn_s_barrier();                                             \
} while (0)

__global__ __launch_bounds__(256, 2)
void qlinear_fb_kernel(const float* __restrict__ A,
                       const int*   __restrict__ Q,
                       const float* __restrict__ scale,
                       const float* __restrict__ bias,
                       const float* __restrict__ rowsum,
                       float* __restrict__ C,
                       int M, int N, int K)
{
  __shared__ unsigned short sA[2][BM][BK];
  __shared__ unsigned short sB[2][BN][BK];

  const int tid  = threadIdx.x;
  const int lane = tid & 63;
  const int wave = tid >> 6;
  const int wr   = wave >> 1;
  const int wc   = wave & 1;

  const int nbm = M / BM;
  const int nwg = gridDim.x;
  int wgid = blockIdx.x;
  if ((nwg & 7) == 0) wgid = (wgid & 7) * (nwg >> 3) + (wgid >> 3);
  const int bm   = wgid % nbm;
  const int bn   = wgid / nbm;
  const int row0 = bm * BM;
  const int col0 = bn * BN;

  const int sr   = tid >> 4;
  const int scol = (tid & 15) << 2;
  const int swzc = scol ^ ((sr & 7) << 3);

  const float* Abase = A + (size_t)(row0 + sr) * K + scol;
  const int*   Qbase = Q + (size_t)(col0 + sr) * K + scol;

  f32x4 acc[2][4];
#pragma unroll
  for (int i = 0; i < 2; ++i)
#pragma unroll
    for (int j = 0; j < 4; ++j) acc[i][j] = (f32x4)0.0f;

  f32x4 a0_0, a0_1, a0_2, a0_3;
  f32x4 a1_0, a1_1, a1_2, a1_3;
  i32x4 q0_0, q0_1, q0_2, q0_3, q0_4, q0_5, q0_6, q0_7;
  i32x4 q1_0, q1_1, q1_2, q1_3, q1_4, q1_5, q1_6, q1_7;

  const int NT = K / BK;

  LOADS(0, 0);
  LOADS(1, BK);
  __builtin_amdgcn_sched_barrier(0);
  STORES(0, 0);
  BARX();

#pragma unroll 1
  for (int t = 0; t < NT; t += 2) {
    const int ke0 = (t + 2 < NT ? t + 2 : NT - 1) * BK;
    const int ke1 = (t + 3 < NT ? t + 3 : NT - 1) * BK;

    LOADS(0, ke0);
    __builtin_amdgcn_sched_barrier(0);
    COMPUTE(0);
    STORES(1, 1);
    BARX();

    LOADS(1, ke1);
    __builtin_amdgcn_sched_barrier(0);
    COMPUTE(1);
    STORES(0, 0);
    BARX();
  }

  const int cl = lane & 15;
  const int rb = row0 + wr * 32 + ((lane >> 4) << 2);
  float rs128[2][4];
#pragma unroll
  for (int mi = 0; mi < 2; ++mi)
#pragma unroll
    for (int r = 0; r < 4; ++r)
      rs128[mi][r] = 128.0f * rowsum[rb + mi * 16 + r];

#pragma unroll
  for (int ni = 0; ni < 4; ++ni) {
    const int n = col0 + wc * 64 + ni * 16 + cl;
    const float s = scale[n];
    const float b = bias[n];
#pragma unroll
    for (int mi = 0; mi < 2; ++mi) {
#pragma unroll
      for (int r = 0; r < 4; ++r) {
        C[(size_t)(rb + mi * 16 + r) * N + n] = (acc[mi][ni][r] - rs128[mi][r]) * s + b;
      }
    }
  }
}

extern "C" void kernel_launch(void* const* d_in, const int* in_sizes, int n_in,
                              void* d_out, int out_size, void* d_ws, size_t ws_size,
                              hipStream_t stream) {
  const float* inp   = (const float*)d_in[0];
  const int*   qw    = (const int*)d_in[1];
  const float* scale = (const float*)d_in[2];
  const float* bias  = (const float*)d_in[3];
  float*       out   = (float*)d_out;

  const int OUT = in_sizes[3];            // 11008
  const int IN  = in_sizes[1] / OUT;      // 4096
  const int M   = in_sizes[0] / IN;       // 512

  const size_t qbf_bytes = (size_t)OUT * IN * 2;   // 90.2 MB
  const size_t abf_bytes = (size_t)M * IN * 2;     //  4.2 MB
  const int grid = (M / BM) * (OUT / BN);          // 688

  if (ws_size >= qbf_bytes + abf_bytes) {
    unsigned short* Qbf = (unsigned short*)d_ws;
    unsigned short* Abf = (unsigned short*)((char*)d_ws + qbf_bytes);

    cvtA_kernel<<<1024, 256, 0, stream>>>(inp, Abf, (M * IN) >> 2);
    cvtQ_kernel<<<4096, 256, 0, stream>>>(qw, Qbf, (int)(((size_t)OUT * IN) >> 2));
    qgemm_kernel<<<grid, 256, 0, stream>>>(Abf, Qbf, scale, bias, out, M, OUT, IN);
  } else {
    float* rs = (float*)d_ws;
    rowsum_kernel<<<M, 256, 0, stream>>>(inp, rs, IN);
    qlinear_fb_kernel<<<grid, 256, 0, stream>>>(inp, qw, scale, bias, rs, out, M, OUT, IN);
  }
}